// Round 15
// baseline (205.434 us; speedup 1.0000x reference)
//
#include <hip/hip_runtime.h>

// ---------- types ----------
typedef __bf16 bf16x8 __attribute__((ext_vector_type(8)));
typedef float f32x4 __attribute__((ext_vector_type(4)));
typedef unsigned short u16x8 __attribute__((ext_vector_type(8)));

__device__ inline unsigned short f2bf(float f) {
  union { float f; unsigned u; } a; a.f = f;
  return (unsigned short)((a.u + 0x7fffu + ((a.u >> 16) & 1u)) >> 16); // RNE
}
__device__ inline float bf2f(unsigned short h) {
  union { unsigned u; float f; } a; a.u = ((unsigned)h) << 16;
  return a.f;
}

// ---------- fp32 -> bf16 conversion for Wq,Wk,Wv only (12 MB) ----------
__global__ __launch_bounds__(256) void cvtW(const float* __restrict__ Wq,
                                            const float* __restrict__ Wk,
                                            const float* __restrict__ Wv,
                                            unsigned short* __restrict__ Wb) {
  int i = blockIdx.x * 256 + threadIdx.x;   // 786432 float4 groups
  int idx = i >> 18;                        // 262144 float4 per W
  int off = i & 262143;
  const float* s = (idx == 0) ? Wq : ((idx == 1) ? Wk : Wv);
  float4 v = ((const float4*)s)[off];
  ushort4 o;
  o.x = f2bf(v.x); o.y = f2bf(v.y); o.z = f2bf(v.z); o.w = f2bf(v.w);
  ((ushort4*)(Wb + idx * 1048576))[off] = o;
}

#define G2L(gp, lp) __builtin_amdgcn_global_load_lds( \
    (const __attribute__((address_space(1))) void*)(gp), \
    (__attribute__((address_space(3))) void*)(lp), 16, 0, 0)

#define MFMA_(d, a, b) d = __builtin_amdgcn_mfma_f32_16x16x32_bf16(a, b, d, 0, 0, 0)
#define SB0() __builtin_amdgcn_sched_barrier(0)
#define LGKM(n) do { asm volatile("s_waitcnt lgkmcnt(" #n ")" ::: "memory"); SB0(); } while (0)
#define VMC(n) do { asm volatile("s_waitcnt vmcnt(" #n ")" ::: "memory"); SB0(); } while (0)

// =====================================================================
// gemmP v5: ACVT on the best-ratio geometry.
// BM=256 BN=128 BK=32, 256 thr = 4 waves of 64x128 (375 LDS-B/MFMA vs
// r14's 500; acc[4][8]=128 AGPR + ~110 VGPR -> 2 waves/SIMD).
// LDS 56KB = A 2x16KB + B 3x8KB -> 2 WGs/CU. Grid 768 (1.5 rounds).
// Deep pipeline: ldA(t+2)+stageB(t+2) at TOP of tile t (10 vmem);
// bottom wait = counted VMC(10) (retire t+1 exactly, keep t+2 in
// flight); dual areg sets pair-unrolled. A relayed (plain-cast cvt ->
// 8x ds_write_b64) into the r9-VERIFIED row-paired 0-conflict layout:
// line L (128B) holds rows {2L,2L+1}; 16B slot ((par<<2)|kq)^(L&7);
// reads use the same involution. LGKM(0) pre-barrier = cross-wave
// ds_write visibility (the only wait the compiler can't infer).
// =====================================================================
struct PJ {
  const float* A0; const float* A1; const float* A2;
  const unsigned short* B;                  // Wb (3 matrices)
  unsigned short* outQ; unsigned short* outK; unsigned short* outV;
  const float* biasQ; const float* biasK; const float* biasV;
};

__global__ __launch_bounds__(256) void gemmP(PJ p) {
  extern __shared__ char smem[];            // 57344: A 2x16384 | B 3x8192
  char* smA = smem;
  char* smB = smem + 32768;
  const int tid = threadIdx.x, lane = tid & 63, wid = tid >> 6;
  const int wm = wid;                       // 4 waves, wave tile 64x128

  // XCD swizzle, grid (8,32,3) = 768 WGs (768%8==0)
  int orig = blockIdx.x + 8 * (blockIdx.y + 32 * blockIdx.z);
  int wg = (orig & 7) * 96 + (orig >> 3);
  int bx = wg & 7; int t2 = wg >> 3; int by = t2 & 31; int z = t2 >> 5;
  const int m0 = by << 8, n0 = bx << 7;

  const float* Az = (z == 0) ? p.A0 : ((z == 1) ? p.A1 : p.A2);

  // A fp32 source: chunk c reads row c*32 + (tid>>3), 16B unit (tid&7)
  const char* srcA0 = (const char*)Az + ((long long)m0 + (tid >> 3)) * 4096
                    + ((tid & 7) << 4);
  // B staging, row-paired inverse-permuted source (r9-verified):
  // dest line L = c*32 + (tid>>3), slot s = tid&7; sg = s^(L&7)
  // -> src row = c*64 + 2*(tid>>3) + (sg>>2), kbyte = (sg&3)*16
  const int L0 = tid >> 3;
  const int sgB = (tid & 7) ^ (L0 & 7);
  const char* srcB = (const char*)(p.B + (long long)z * 1048576
                     + (long long)(n0 + 2 * L0 + (sgB >> 2)) * 1024)
                   + ((sgB & 3) << 4);

  // wrA constants: thread writes 8B for (row rc, k-group kq, half h)
  const int kqW = (tid & 7) >> 1;
  const int hW = (tid & 1) << 3;

  // ds_read offsets (row-paired): row R, k-half kh=lane>>4:
  // byte = (R>>1)<<7 + ((((R&1)<<2)|kh) ^ ((R>>1)&7))<<4
  const int kh = lane >> 4;
  const int Ra0 = (wm << 6) + (lane & 15);
  const int Rb0 = lane & 15;

  f32x4 acc[4][8];
#pragma unroll
  for (int i = 0; i < 4; ++i)
#pragma unroll
    for (int j = 0; j < 8; ++j) acc[i][j] = (f32x4){0.f, 0.f, 0.f, 0.f};

  float4 aregA[8], aregB[8];
  bf16x8 aLo[2], aHi[2], bLo[4], bHi[4];

  auto ldA = [&](int t, float4 (&ar)[8]) {  // 8 coalesced global_load_dwordx4
    const char* s = srcA0 + (long long)t * 128;
#pragma unroll
    for (int c = 0; c < 8; ++c)
      ar[c] = *(const float4*)(s + (long long)c * 32 * 4096);
  };
  auto wrA = [&](int t, float4 (&ar)[8]) {  // plain-cast cvt + 8x ds_write_b64
    char* dA = smA + ((t & 1) << 14);
#pragma unroll
    for (int c = 0; c < 8; ++c) {
      const int rc = (c << 5) + (tid >> 3);
      const int line = rc >> 1, par = rc & 1;
      float4 v = ar[c];
      union { __bf16 b[4]; unsigned long long u; } o;
      o.b[0] = (__bf16)v.x; o.b[1] = (__bf16)v.y;
      o.b[2] = (__bf16)v.z; o.b[3] = (__bf16)v.w;
      *(unsigned long long*)(dA + (line << 7)
          + ((((par << 2) | kqW) ^ (line & 7)) << 4) + hW) = o.u;
    }
  };
  auto stageB = [&](int t, int b) {         // 2 G2L chunks
    char* dB = smB + (b << 13) + (tid << 4);
    const char* sB = srcB + (long long)t * 64;
#pragma unroll
    for (int c = 0; c < 2; ++c)
      G2L(sB + (long long)c * 64 * 2048, dB + (c << 12));
  };
  auto readA = [&](int b, int half, bf16x8 (&dst)[2]) {     // 2 ds_read_b128
    const char* ra = smA + (b << 14);
#pragma unroll
    for (int f = 0; f < 2; ++f) {
      const int R = Ra0 + ((half * 2 + f) << 4);
      dst[f] = *(const bf16x8*)(ra + ((R >> 1) << 7)
               + (((((R & 1) << 2) | kh) ^ ((R >> 1) & 7)) << 4));
    }
  };
  auto readB = [&](int b, int half, bf16x8 (&dst)[4]) {     // 4 ds_read_b128
    const char* rb = smB + (b << 13);
#pragma unroll
    for (int f = 0; f < 4; ++f) {
      const int R = Rb0 + ((half * 4 + f) << 4);
      dst[f] = *(const bf16x8*)(rb + ((R >> 1) << 7)
               + (((((R & 1) << 2) | kh) ^ ((R >> 1) & 7)) << 4));
    }
  };
  auto quadP = [&](int qa, int qb, bf16x8 (&A)[2], bf16x8 (&B)[4]) {
    __builtin_amdgcn_s_setprio(1);
#pragma unroll
    for (int mi = 0; mi < 2; ++mi)
#pragma unroll
      for (int ni = 0; ni < 4; ++ni)
        MFMA_(acc[qa * 2 + mi][qb * 4 + ni], A[mi], B[ni]);
    __builtin_amdgcn_s_setprio(0);
  };

  const int NT = 32;
  int b0 = 0, b1 = 1, b2 = 2;               // B buf of t, t+1, t+2

  // ---- prologue ----
  ldA(0, aregA); stageB(0, 0);              // 10
  ldA(1, aregB); stageB(1, 1);              // 10 (20 outstanding)
  VMC(10);                                  // tile0's retired
  wrA(0, aregA);
  LGKM(0);
  __builtin_amdgcn_s_barrier();
  readA(0, 0, aLo); readB(0, 0, bLo);
  SB0();

  auto body = [&](int t, float4 (&arW)[8], float4 (&arL)[8]) {
    const bool pf1 = (t + 1) < NT, pf2 = (t + 2) < NT;
    if (pf2) { ldA(t + 2, arL); stageB(t + 2, b2); }  // 10 vmem
    readA(t & 1, 1, aHi);                    // +2 lgkm (6 pre-read out)
    SB0();
    LGKM(2);                                 // aLo,bLo ready (aHi pends)
    quadP(0, 0, aLo, bLo);
    readB(b0, 1, bHi);                       // +4
    SB0();
    LGKM(4);                                 // aHi ready (bHi pends)
    quadP(1, 0, aHi, bLo);
    LGKM(0);                                 // bHi ready
    quadP(0, 1, aLo, bHi);
    quadP(1, 1, aHi, bHi);
    if (pf2)      { VMC(10); }               // t+1 retired; t+2 in flight
    else          { VMC(0);  }
    if (pf1) wrA(t + 1, arW);                // other A buf (no WAR)
    LGKM(0);                                 // ds_writes visible pre-barrier
    __builtin_amdgcn_s_barrier();
    if (pf1) { readA((t + 1) & 1, 0, aLo); readB(b1, 0, bLo); }
    SB0();
    int tmp = b0; b0 = b1; b1 = b2; b2 = tmp;
  };
  for (int t = 0; t < NT; t += 2) { body(t, aregB, aregA); body(t + 1, aregA, aregB); }

  // ---- epilogue: bias add; z<2 row-major; z==2 transposed vT[b][d][s] ----
  const int c0 = lane & 15, r0 = (lane >> 4) << 2;
  if (z < 2) {
    unsigned short* O = (z == 0) ? p.outQ : p.outK;
    const float* bias = (z == 0) ? p.biasQ : p.biasK;
#pragma unroll
    for (int mi = 0; mi < 4; ++mi) {
      const int grow = m0 + (wm << 6) + (mi << 4) + r0;
#pragma unroll
      for (int ni = 0; ni < 8; ++ni) {
        const int gcol = n0 + (ni << 4) + c0;
        const float bb = bias[gcol];
#pragma unroll
        for (int rr = 0; rr < 4; ++rr)
          O[(long long)(grow + rr) * 1024 + gcol] = f2bf(acc[mi][ni][rr] + bb);
      }
    }
  } else {
#pragma unroll
    for (int mi = 0; mi < 4; ++mi) {
      const int grow = m0 + (wm << 6) + (mi << 4) + r0;
      const int bb = grow >> 11, s = grow & 2047;
#pragma unroll
      for (int ni = 0; ni < 8; ++ni) {
        const int d = n0 + (ni << 4) + c0;
        const float ba = p.biasV[d];
        ushort4 pk;
        pk.x = f2bf(acc[mi][ni][0] + ba);
        pk.y = f2bf(acc[mi][ni][1] + ba);
        pk.z = f2bf(acc[mi][ni][2] + ba);
        pk.w = f2bf(acc[mi][ni][3] + ba);
        *(ushort4*)(p.outV + ((long long)bb << 21) + (long long)d * 2048 + s) = pk;
      }
    }
  }
}

// =====================================================================
// gemm2: r4-exact bf16 GEMM (BK=64, best measured for QK/PV).
// =====================================================================
#define EPI_SCALE 1
#define EPI_OUT 2

struct GP {
  const unsigned short* A;
  const unsigned short* B;
  unsigned short* C;            // bf16 (EPI_SCALE) or float* (EPI_OUT)
  long long batchA, batchB, batchC;
  int lda, ldb, ldc, K;
  float scale;
};

template<int BM, int BN, int WMW, int WNW, int EPI>
__global__ __launch_bounds__(512, 2) void gemm2(GP p) {
  constexpr int NWN = BN / WNW;
  constexpr int AMF = WMW / 16, BNF = WNW / 16;
  constexpr int AH = AMF / 2, BH = BNF / 2;
  constexpr int AF_N = AH * 2;
  constexpr int NBA = BM / 64, NBB = BN / 64;
  static_assert((BM / WMW) * NWN == 8, "8 waves");
  static_assert(BNF == 4, "lgkm immediates assume BNF==4");

  extern __shared__ char smem[];
  char* smA = smem;
  char* smB = smem + 2 * BM * 128;

  const int tid = threadIdx.x;
  const int lane = tid & 63;
  const int wid = tid >> 6;
  const int wm = wid / NWN, wn = wid % NWN;

  const int gx = gridDim.x, gy = gridDim.y;
  const int nwg = gx * gy * (int)gridDim.z;
  int orig = blockIdx.x + gx * (blockIdx.y + gy * blockIdx.z);
  int qq = nwg >> 3, rr_ = nwg & 7;
  int xcd = orig & 7, sl = orig >> 3;
  int wg = (xcd < rr_ ? xcd * (qq + 1) : rr_ * (qq + 1) + (xcd - rr_) * qq) + sl;
  int bx = wg % gx;
  int t2 = wg / gx;
  int by = t2 % gy;
  int z  = t2 / gy;

  const int m0 = by * BM, n0 = bx * BN;

  const long long lda2 = (long long)p.lda * 2;
  const long long ldb2 = (long long)p.ldb * 2;
  const char* Abase = (const char*)(p.A + (long long)z * p.batchA) + (long long)m0 * lda2;
  const char* Bbase = (const char*)(p.B + (long long)z * p.batchB) + (long long)n0 * ldb2;

  const int trow = tid >> 3;
  const int cs = (((tid & 7) ^ (trow & 7)) << 4);
  const char* srcA = Abase + (long long)trow * lda2 + cs;
  const char* srcB = Bbase + (long long)trow * ldb2 + cs;

  const int NT = p.K >> 6;

  const int aRowB = ((wm * WMW + (lane & 15)) << 7);
  const int bRowB = ((wn * WNW + (lane & 15)) << 7);
  const int csw = (lane & 7) << 4;
  const int ck0 = (((lane >> 4) << 4)) ^ csw;
  const int ck1 = ((((lane >> 4) << 4)) | 64) ^ csw;

  f32x4 acc[AMF][BNF];
#pragma unroll
  for (int i = 0; i < AMF; ++i)
#pragma unroll
    for (int j = 0; j < BNF; ++j) acc[i][j] = (f32x4){0.f, 0.f, 0.f, 0.f};

  bf16x8 aLo[AH][2], aHi[AH][2], bLo[BH][2], bHi[BH][2];

  auto stage = [&](int t) {
    char* dA = smA + (t & 1) * (BM * 128) + (tid << 4);
    char* dB = smB + (t & 1) * (BN * 128) + (tid << 4);
    const char* sA = srcA + (long long)t * 128;
    const char* sB = srcB + (long long)t * 128;
#pragma unroll
    for (int c = 0; c < NBA; ++c) G2L(sA + (long long)c * (lda2 << 6), dA + c * 8192);
#pragma unroll
    for (int c = 0; c < NBB; ++c) G2L(sB + (long long)c * (ldb2 << 6), dB + c * 8192);
  };
  auto readAh = [&](int t, int half, bf16x8 (&dst)[AH][2]) {
    const char* ra = smA + (t & 1) * (BM * 128) + aRowB + half * (AH * 2048);
#pragma unroll
    for (int mi = 0; mi < AH; ++mi) {
      dst[mi][0] = *(const bf16x8*)(ra + mi * 2048 + ck0);
      dst[mi][1] = *(const bf16x8*)(ra + mi * 2048 + ck1);
    }
  };
  auto readBh = [&](int t, int half, bf16x8 (&dst)[BH][2]) {
    const char* rb = smB + (t & 1) * (BN * 128) + bRowB + half * (BH * 2048);
#pragma unroll
    for (int ni = 0; ni < BH; ++ni) {
      dst[ni][0] = *(const bf16x8*)(rb + ni * 2048 + ck0);
      dst[ni][1] = *(const bf16x8*)(rb + ni * 2048 + ck1);
    }
  };
  auto quad = [&](int qa, int qb, bf16x8 (&A)[AH][2], bf16x8 (&B)[BH][2]) {
    __builtin_amdgcn_s_setprio(1);
#pragma unroll
    for (int mi = 0; mi < AH; ++mi)
#pragma unroll
      for (int ni = 0; ni < BH; ++ni) {
        MFMA_(acc[qa * AH + mi][qb * BH + ni], A[mi][0], B[ni][0]);
        MFMA_(acc[qa * AH + mi][qb * BH + ni], A[mi][1], B[ni][1]);
      }
    __builtin_amdgcn_s_setprio(0);
  };

  stage(0); stage(1);
  if constexpr (NBA + NBB == 8) VMC(8); else VMC(6);
  __builtin_amdgcn_s_barrier();
  readAh(0, 0, aLo); readBh(0, 0, bLo);
  SB0();

  for (int t = 0; t < NT; ++t) {
    readAh(t, 1, aHi);
    SB0();
    if constexpr (AF_N == 8) LGKM(8); else LGKM(4);
    quad(0, 0, aLo, bLo);
    readBh(t, 1, bHi);
    SB0();
    LGKM(4);
    quad(1, 0, aHi, bLo);
    LGKM(0);
    quad(0, 1, aLo, bHi);
    quad(1, 1, aHi, bHi);
    VMC(0);
    __builtin_amdgcn_s_barrier();
    if (t + 2 < NT) stage(t + 2);
    if (t + 1 < NT) { readAh(t + 1, 0, aLo); readBh(t + 1, 0, bLo); }
    SB0();
  }

  const int c0 = lane & 15;
  const int r0 = (lane >> 4) << 2;
  if constexpr (EPI == EPI_SCALE) {
    unsigned short* Cz = p.C + (long long)z * p.batchC;
#pragma unroll
    for (int mi = 0; mi < AMF; ++mi) {
      const int grow = m0 + wm * WMW + (mi << 4) + r0;
#pragma unroll
      for (int ni = 0; ni < BNF; ++ni) {
        const int gcol = n0 + wn * WNW + (ni << 4) + c0;
#pragma unroll
        for (int rr = 0; rr < 4; ++rr)
          Cz[(long long)(grow + rr) * p.ldc + gcol] = f2bf(acc[mi][ni][rr] * p.scale);
      }
    }
  } else {
    float* Cz = (float*)p.C + (long long)z * p.batchC;
#pragma unroll
    for (int mi = 0; mi < AMF; ++mi) {
      const int grow = m0 + wm * WMW + (mi << 4) + r0;
#pragma unroll
      for (int ni = 0; ni < BNF; ++ni) {
        const int gcol = n0 + wn * WNW + (ni << 4) + c0;
#pragma unroll
        for (int rr = 0; rr < 4; ++rr)
          Cz[(long long)(grow + rr) * p.ldc + gcol] = acc[mi][ni][rr] * p.scale;
      }
    }
  }
}

// ---------- row softmax over S[4][2048][2048] (bf16, in place) ----------
__global__ __launch_bounds__(256) void softmax_rows(unsigned short* __restrict__ S) {
  const size_t row = blockIdx.x;
  unsigned short* pp = S + row * 2048;
  const int t = threadIdx.x, lane = t & 63, wave = t >> 6;
  u16x8 h = ((const u16x8*)pp)[t];
  float x[8];
#pragma unroll
  for (int j = 0; j < 8; ++j) x[j] = bf2f(h[j]);
  float m = x[0];
#pragma unroll
  for (int j = 1; j < 8; ++j) m = fmaxf(m, x[j]);
#pragma unroll
  for (int off = 32; off >= 1; off >>= 1) m = fmaxf(m, __shfl_xor(m, off, 64));
  __shared__ float rmax[4], rsum[4];
  if (lane == 0) rmax[wave] = m;
  __syncthreads();
  m = fmaxf(fmaxf(rmax[0], rmax[1]), fmaxf(rmax[2], rmax[3]));
  float e[8], sum = 0.f;
#pragma unroll
  for (int j = 0; j < 8; ++j) { e[j] = __expf(x[j] - m); sum += e[j]; }
#pragma unroll
  for (int off = 32; off >= 1; off >>= 1) sum += __shfl_xor(sum, off, 64);
  if (lane == 0) rsum[wave] = sum;
  __syncthreads();
  sum = rsum[0] + rsum[1] + rsum[2] + rsum[3];
  const float inv = 1.f / sum;
  u16x8 o;
#pragma unroll
  for (int j = 0; j < 8; ++j) o[j] = f2bf(e[j] * inv);
  ((u16x8*)pp)[t] = o;
}

// ---------- launch ----------
extern "C" void kernel_launch(void* const* d_in, const int* in_sizes, int n_in,
                              void* d_out, int out_size, void* d_ws, size_t ws_size,
                              hipStream_t stream) {
  const float* q  = (const float*)d_in[0];
  const float* k  = (const float*)d_in[1];
  const float* v  = (const float*)d_in[2];
  const float* Wq = (const float*)d_in[3];
  const float* bq = (const float*)d_in[4];
  const float* Wk = (const float*)d_in[5];
  const float* bk = (const float*)d_in[6];
  const float* Wv = (const float*)d_in[7];
  const float* bv = (const float*)d_in[8];

  // workspace (u16 elems): S 32MB, Wb 6MB, qb 16MB, kb 16MB, vT 16MB = 86MB
  unsigned short* S  = (unsigned short*)d_ws;
  unsigned short* Wb = S + 16777216;
  unsigned short* qb = Wb + 3145728;
  unsigned short* kb = qb + 8388608;
  unsigned short* vT = kb + 8388608;

  (void)hipFuncSetAttribute((const void*)gemmP,
      hipFuncAttributeMaxDynamicSharedMemorySize, 57344);
  (void)hipFuncSetAttribute((const void*)gemm2<256,256,128,64,EPI_SCALE>,
      hipFuncAttributeMaxDynamicSharedMemorySize, 131072);
  (void)hipFuncSetAttribute((const void*)gemm2<256,128,64,64,EPI_OUT>,
      hipFuncAttributeMaxDynamicSharedMemorySize, 98304);

  cvtW<<<3072, 256, 0, stream>>>(Wq, Wk, Wv, Wb);

  // fused q/k/v projections, A fp32 converted in-register during staging:
  // per z, M=8192, N=1024, K=1024; 768 WGs (256x128, 256 thr), 2 WGs/CU
  PJ pj{};
  pj.A0 = q; pj.A1 = k; pj.A2 = v;
  pj.B = Wb;
  pj.outQ = qb; pj.outK = kb; pj.outV = vT;
  pj.biasQ = bq; pj.biasK = bk; pj.biasV = bv;
  gemmP<<<dim3(8, 32, 3), 256, 57344, stream>>>(pj);

  // scores = q @ k^T * scale : per batch M=2048, N=2048, K=1024 (256 WGs)
  GP gs{};
  gs.A = qb; gs.batchA = 2097152; gs.lda = 1024;
  gs.B = kb; gs.batchB = 2097152; gs.ldb = 1024;
  gs.C = S;  gs.batchC = 4194304; gs.ldc = 2048;
  gs.K = 1024; gs.scale = 0.03125f;
  gemm2<256,256,128,64,EPI_SCALE><<<dim3(8, 8, 4), 512, 131072, stream>>>(gs);

  softmax_rows<<<8192, 256, 0, stream>>>(S);

  // out = P @ V : M=2048, N=1024, K=2048 per batch (256 WGs)
  GP gv{};
  gv.A = S;  gv.batchA = 4194304; gv.lda = 2048;
  gv.B = vT; gv.batchB = 2097152; gv.ldb = 2048;
  gv.C = (unsigned short*)d_out; gv.batchC = 2097152; gv.ldc = 1024;
  gv.K = 2048; gv.scale = 1.f;
  gemm2<256,128,64,64,EPI_OUT><<<dim3(8, 8, 4), 512, 98304, stream>>>(gv);
}

// Round 16
// 167.332 us; speedup vs baseline: 1.2277x; 1.2277x over previous
//
#include <hip/hip_runtime.h>

// ---------- types ----------
typedef __bf16 bf16x8 __attribute__((ext_vector_type(8)));
typedef float f32x4 __attribute__((ext_vector_type(4)));
typedef unsigned short u16x8 __attribute__((ext_vector_type(8)));

__device__ inline unsigned short f2bf(float f) {
  union { float f; unsigned u; } a; a.f = f;
  return (unsigned short)((a.u + 0x7fffu + ((a.u >> 16) & 1u)) >> 16); // RNE
}
__device__ inline float bf2f(unsigned short h) {
  union { unsigned u; float f; } a; a.u = ((unsigned)h) << 16;
  return a.f;
}

// ---------- fp32 -> bf16 conversion for Wq,Wk,Wv only (12 MB) ----------
__global__ __launch_bounds__(256) void cvtW(const float* __restrict__ Wq,
                                            const float* __restrict__ Wk,
                                            const float* __restrict__ Wv,
                                            unsigned short* __restrict__ Wb) {
  int i = blockIdx.x * 256 + threadIdx.x;   // 786432 float4 groups
  int idx = i >> 18;                        // 262144 float4 per W
  int off = i & 262143;
  const float* s = (idx == 0) ? Wq : ((idx == 1) ? Wk : Wv);
  float4 v = ((const float4*)s)[off];
  ushort4 o;
  o.x = f2bf(v.x); o.y = f2bf(v.y); o.z = f2bf(v.z); o.w = f2bf(v.w);
  ((ushort4*)(Wb + idx * 1048576))[off] = o;
}

#define G2L(gp, lp) __builtin_amdgcn_global_load_lds( \
    (const __attribute__((address_space(1))) void*)(gp), \
    (__attribute__((address_space(3))) void*)(lp), 16, 0, 0)

#define MFMA_(d, a, b) d = __builtin_amdgcn_mfma_f32_16x16x32_bf16(a, b, d, 0, 0, 0)
#define SB0() __builtin_amdgcn_sched_barrier(0)
#define LGKM(n) do { asm volatile("s_waitcnt lgkmcnt(" #n ")" ::: "memory"); SB0(); } while (0)
#define VMC(n) do { asm volatile("s_waitcnt vmcnt(" #n ")" ::: "memory"); SB0(); } while (0)

// =====================================================================
// gemmP (r14-exact, best measured): ACVT with deep prefetch.
// BM=BN=128, BK=64, 256 thr = 4 waves (2x2). LDS 80KB = A 2x16KB +
// B 3x16KB -> 2 WGs/CU. ldA(t+2)+stageB(t+2) at TOP of tile t; bottom
// wait counted VMC(12) (retire t+1 exactly, keep t+2 in flight).
// Plain-cast cvt (v_cvt_pk). A layout r4-verified 0-conflict.
// =====================================================================
struct PJ {
  const float* A0; const float* A1; const float* A2;
  const unsigned short* B;                  // Wb (3 matrices)
  unsigned short* outQ; unsigned short* outK; unsigned short* outV;
  const float* biasQ; const float* biasK; const float* biasV;
};

__global__ __launch_bounds__(256) void gemmP(PJ p) {
  extern __shared__ char smem[];            // 81920: A 2x16384 | B 3x16384
  char* smA = smem;
  char* smB = smem + 32768;
  const int tid = threadIdx.x, lane = tid & 63, wid = tid >> 6;
  const int wm = wid >> 1, wn = wid & 1;

  // XCD swizzle, grid (8,64,3) = 1536 WGs (1536%8==0)
  int orig = blockIdx.x + 8 * (blockIdx.y + 64 * blockIdx.z);
  int wg = (orig & 7) * 192 + (orig >> 3);
  int bx = wg & 7; int t2 = wg >> 3; int by = t2 & 63; int z = t2 >> 6;
  const int m0 = by << 7, n0 = bx << 7;

  const float* Az = (z == 0) ? p.A0 : ((z == 1) ? p.A1 : p.A2);

  const char* srcA0 = (const char*)Az + ((long long)m0 + (tid >> 4)) * 4096
                    + ((tid & 15) << 4);
  const int trow = tid >> 3;
  const int cs = (((tid & 7) ^ (trow & 7)) << 4);
  const char* srcB = (const char*)(p.B + (long long)z * 1048576
                                   + (long long)(n0 + trow) * 1024) + cs;

  const int aRowB = (((wm << 6) + (lane & 15)) << 7);
  const int bRowB = (((wn << 6) + (lane & 15)) << 7);
  const int csw = (lane & 7) << 4;
  const int ck0 = (((lane >> 4) << 4)) ^ csw;
  const int ck1 = ((((lane >> 4) << 4)) | 64) ^ csw;

  f32x4 acc[4][4];
#pragma unroll
  for (int i = 0; i < 4; ++i)
#pragma unroll
    for (int j = 0; j < 4; ++j) acc[i][j] = (f32x4){0.f, 0.f, 0.f, 0.f};

  float4 aregA[8], aregB[8];
  bf16x8 aLo[2][2], aHi[2][2], bLo[2][2], bHi[2][2];

  auto ldA = [&](int t, float4 (&ar)[8]) {
    const char* s = srcA0 + (long long)t * 256;
#pragma unroll
    for (int c = 0; c < 8; ++c)
      ar[c] = *(const float4*)(s + (long long)c * 65536);
  };
  auto wrA = [&](int t, float4 (&ar)[8]) {
    char* dA = smA + ((t & 1) << 14);
    const int g = (tid & 15) >> 1;
    const int hb = (tid & 1) << 3;
#pragma unroll
    for (int c = 0; c < 8; ++c) {
      const int rc = (c << 4) + (tid >> 4);
      float4 v = ar[c];
      union { __bf16 b[4]; ushort4 u; } o;
      o.b[0] = (__bf16)v.x; o.b[1] = (__bf16)v.y;
      o.b[2] = (__bf16)v.z; o.b[3] = (__bf16)v.w;
      *(ushort4*)(dA + (rc << 7) + ((g ^ (rc & 7)) << 4) + hb) = o.u;
    }
  };
  auto stageB = [&](int t, int b) {
    char* dB = smB + (b << 14) + (tid << 4);
    const char* sB = srcB + (long long)t * 128;
#pragma unroll
    for (int c = 0; c < 4; ++c)
      G2L(sB + (long long)c * 65536, dB + (c << 12));
  };
  auto readAh = [&](int b, int half, bf16x8 (&dst)[2][2]) {
    const char* ra = smA + (b << 14) + aRowB + (half << 12);
#pragma unroll
    for (int mi = 0; mi < 2; ++mi) {
      dst[mi][0] = *(const bf16x8*)(ra + (mi << 11) + ck0);
      dst[mi][1] = *(const bf16x8*)(ra + (mi << 11) + ck1);
    }
  };
  auto readBh = [&](int b, int half, bf16x8 (&dst)[2][2]) {
    const char* rb = smB + (b << 14) + bRowB + (half << 12);
#pragma unroll
    for (int ni = 0; ni < 2; ++ni) {
      dst[ni][0] = *(const bf16x8*)(rb + (ni << 11) + ck0);
      dst[ni][1] = *(const bf16x8*)(rb + (ni << 11) + ck1);
    }
  };
  auto quad = [&](int qa, int qb, bf16x8 (&A)[2][2], bf16x8 (&B)[2][2]) {
    __builtin_amdgcn_s_setprio(1);
#pragma unroll
    for (int mi = 0; mi < 2; ++mi)
#pragma unroll
      for (int ni = 0; ni < 2; ++ni) {
        MFMA_(acc[qa * 2 + mi][qb * 2 + ni], A[mi][0], B[ni][0]);
        MFMA_(acc[qa * 2 + mi][qb * 2 + ni], A[mi][1], B[ni][1]);
      }
    __builtin_amdgcn_s_setprio(0);
  };

  const int NT = 16;
  int b0 = 0, b1 = 1, b2 = 2;               // B buf of t, t+1, t+2

  ldA(0, aregA); stageB(0, 0);
  ldA(1, aregB); stageB(1, 1);
  VMC(12);
  wrA(0, aregA);
  LGKM(0);
  __builtin_amdgcn_s_barrier();
  readAh(0, 0, aLo); readBh(0, 0, bLo);
  SB0();

  auto body = [&](int t, float4 (&arW)[8], float4 (&arL)[8]) {
    const bool pf1 = (t + 1) < NT, pf2 = (t + 2) < NT;
    if (pf2) { ldA(t + 2, arL); stageB(t + 2, b2); }
    readAh(t & 1, 1, aHi);
    SB0();
    LGKM(4);
    quad(0, 0, aLo, bLo);
    readBh(b0, 1, bHi);
    SB0();
    LGKM(4);
    quad(1, 0, aHi, bLo);
    LGKM(0);
    quad(0, 1, aLo, bHi);
    quad(1, 1, aHi, bHi);
    if (pf2) { VMC(12); }
    else     { VMC(0);  }
    if (pf1) wrA(t + 1, arW);
    LGKM(0);
    __builtin_amdgcn_s_barrier();
    if (pf1) { readAh((t + 1) & 1, 0, aLo); readBh(b1, 0, bLo); }
    SB0();
    int tmp = b0; b0 = b1; b1 = b2; b2 = tmp;
  };
  for (int t = 0; t < NT; t += 2) { body(t, aregB, aregA); body(t + 1, aregA, aregB); }

  const int c0 = lane & 15, r0 = (lane >> 4) << 2;
  if (z < 2) {
    unsigned short* O = (z == 0) ? p.outQ : p.outK;
    const float* bias = (z == 0) ? p.biasQ : p.biasK;
#pragma unroll
    for (int mi = 0; mi < 4; ++mi) {
      const int grow = m0 + (wm << 6) + (mi << 4) + r0;
#pragma unroll
      for (int ni = 0; ni < 4; ++ni) {
        const int gcol = n0 + (wn << 6) + (ni << 4) + c0;
        const float bb = bias[gcol];
#pragma unroll
        for (int rr = 0; rr < 4; ++rr)
          O[(long long)(grow + rr) * 1024 + gcol] = f2bf(acc[mi][ni][rr] + bb);
      }
    }
  } else {
#pragma unroll
    for (int mi = 0; mi < 4; ++mi) {
      const int grow = m0 + (wm << 6) + (mi << 4) + r0;
      const int bb = grow >> 11, s = grow & 2047;
#pragma unroll
      for (int ni = 0; ni < 4; ++ni) {
        const int d = n0 + (wn << 6) + (ni << 4) + c0;
        const float ba = p.biasV[d];
        ushort4 pk;
        pk.x = f2bf(acc[mi][ni][0] + ba);
        pk.y = f2bf(acc[mi][ni][1] + ba);
        pk.z = f2bf(acc[mi][ni][2] + ba);
        pk.w = f2bf(acc[mi][ni][3] + ba);
        *(ushort4*)(p.outV + ((long long)bb << 21) + (long long)d * 2048 + s) = pk;
      }
    }
  }
}

// =====================================================================
// gemm2: r4-exact bf16 GEMM (2-buf, used for QK where 3-buf won't fit).
// =====================================================================
#define EPI_SCALE 1
#define EPI_OUT 2

struct GP {
  const unsigned short* A;
  const unsigned short* B;
  unsigned short* C;            // bf16 (EPI_SCALE) or float* (EPI_OUT)
  long long batchA, batchB, batchC;
  int lda, ldb, ldc, K;
  float scale;
};

template<int BM, int BN, int WMW, int WNW, int EPI>
__global__ __launch_bounds__(512, 2) void gemm2(GP p) {
  constexpr int NWN = BN / WNW;
  constexpr int AMF = WMW / 16, BNF = WNW / 16;
  constexpr int AH = AMF / 2, BH = BNF / 2;
  constexpr int AF_N = AH * 2;
  constexpr int NBA = BM / 64, NBB = BN / 64;
  static_assert((BM / WMW) * NWN == 8, "8 waves");
  static_assert(BNF == 4, "lgkm immediates assume BNF==4");

  extern __shared__ char smem[];
  char* smA = smem;
  char* smB = smem + 2 * BM * 128;

  const int tid = threadIdx.x;
  const int lane = tid & 63;
  const int wid = tid >> 6;
  const int wm = wid / NWN, wn = wid % NWN;

  const int gx = gridDim.x, gy = gridDim.y;
  const int nwg = gx * gy * (int)gridDim.z;
  int orig = blockIdx.x + gx * (blockIdx.y + gy * blockIdx.z);
  int qq = nwg >> 3, rr_ = nwg & 7;
  int xcd = orig & 7, sl = orig >> 3;
  int wg = (xcd < rr_ ? xcd * (qq + 1) : rr_ * (qq + 1) + (xcd - rr_) * qq) + sl;
  int bx = wg % gx;
  int t2 = wg / gx;
  int by = t2 % gy;
  int z  = t2 / gy;

  const int m0 = by * BM, n0 = bx * BN;

  const long long lda2 = (long long)p.lda * 2;
  const long long ldb2 = (long long)p.ldb * 2;
  const char* Abase = (const char*)(p.A + (long long)z * p.batchA) + (long long)m0 * lda2;
  const char* Bbase = (const char*)(p.B + (long long)z * p.batchB) + (long long)n0 * ldb2;

  const int trow = tid >> 3;
  const int cs = (((tid & 7) ^ (trow & 7)) << 4);
  const char* srcA = Abase + (long long)trow * lda2 + cs;
  const char* srcB = Bbase + (long long)trow * ldb2 + cs;

  const int NT = p.K >> 6;

  const int aRowB = ((wm * WMW + (lane & 15)) << 7);
  const int bRowB = ((wn * WNW + (lane & 15)) << 7);
  const int csw = (lane & 7) << 4;
  const int ck0 = (((lane >> 4) << 4)) ^ csw;
  const int ck1 = ((((lane >> 4) << 4)) | 64) ^ csw;

  f32x4 acc[AMF][BNF];
#pragma unroll
  for (int i = 0; i < AMF; ++i)
#pragma unroll
    for (int j = 0; j < BNF; ++j) acc[i][j] = (f32x4){0.f, 0.f, 0.f, 0.f};

  bf16x8 aLo[AH][2], aHi[AH][2], bLo[BH][2], bHi[BH][2];

  auto stage = [&](int t) {
    char* dA = smA + (t & 1) * (BM * 128) + (tid << 4);
    char* dB = smB + (t & 1) * (BN * 128) + (tid << 4);
    const char* sA = srcA + (long long)t * 128;
    const char* sB = srcB + (long long)t * 128;
#pragma unroll
    for (int c = 0; c < NBA; ++c) G2L(sA + (long long)c * (lda2 << 6), dA + c * 8192);
#pragma unroll
    for (int c = 0; c < NBB; ++c) G2L(sB + (long long)c * (ldb2 << 6), dB + c * 8192);
  };
  auto readAh = [&](int t, int half, bf16x8 (&dst)[AH][2]) {
    const char* ra = smA + (t & 1) * (BM * 128) + aRowB + half * (AH * 2048);
#pragma unroll
    for (int mi = 0; mi < AH; ++mi) {
      dst[mi][0] = *(const bf16x8*)(ra + mi * 2048 + ck0);
      dst[mi][1] = *(const bf16x8*)(ra + mi * 2048 + ck1);
    }
  };
  auto readBh = [&](int t, int half, bf16x8 (&dst)[BH][2]) {
    const char* rb = smB + (t & 1) * (BN * 128) + bRowB + half * (BH * 2048);
#pragma unroll
    for (int ni = 0; ni < BH; ++ni) {
      dst[ni][0] = *(const bf16x8*)(rb + ni * 2048 + ck0);
      dst[ni][1] = *(const bf16x8*)(rb + ni * 2048 + ck1);
    }
  };
  auto quad = [&](int qa, int qb, bf16x8 (&A)[AH][2], bf16x8 (&B)[BH][2]) {
    __builtin_amdgcn_s_setprio(1);
#pragma unroll
    for (int mi = 0; mi < AH; ++mi)
#pragma unroll
      for (int ni = 0; ni < BH; ++ni) {
        MFMA_(acc[qa * AH + mi][qb * BH + ni], A[mi][0], B[ni][0]);
        MFMA_(acc[qa * AH + mi][qb * BH + ni], A[mi][1], B[ni][1]);
      }
    __builtin_amdgcn_s_setprio(0);
  };

  stage(0); stage(1);
  if constexpr (NBA + NBB == 8) VMC(8); else VMC(6);
  __builtin_amdgcn_s_barrier();
  readAh(0, 0, aLo); readBh(0, 0, bLo);
  SB0();

  for (int t = 0; t < NT; ++t) {
    readAh(t, 1, aHi);
    SB0();
    if constexpr (AF_N == 8) LGKM(8); else LGKM(4);
    quad(0, 0, aLo, bLo);
    readBh(t, 1, bHi);
    SB0();
    LGKM(4);
    quad(1, 0, aHi, bLo);
    LGKM(0);
    quad(0, 1, aLo, bHi);
    quad(1, 1, aHi, bHi);
    VMC(0);
    __builtin_amdgcn_s_barrier();
    if (t + 2 < NT) stage(t + 2);
    if (t + 1 < NT) { readAh(t + 1, 0, aLo); readBh(t + 1, 0, bLo); }
    SB0();
  }

  const int c0 = lane & 15;
  const int r0 = (lane >> 4) << 2;
  if constexpr (EPI == EPI_SCALE) {
    unsigned short* Cz = p.C + (long long)z * p.batchC;
#pragma unroll
    for (int mi = 0; mi < AMF; ++mi) {
      const int grow = m0 + wm * WMW + (mi << 4) + r0;
#pragma unroll
      for (int ni = 0; ni < BNF; ++ni) {
        const int gcol = n0 + wn * WNW + (ni << 4) + c0;
#pragma unroll
        for (int rr = 0; rr < 4; ++rr)
          Cz[(long long)(grow + rr) * p.ldc + gcol] = f2bf(acc[mi][ni][rr] * p.scale);
      }
    }
  } else {
    float* Cz = (float*)p.C + (long long)z * p.batchC;
#pragma unroll
    for (int mi = 0; mi < AMF; ++mi) {
      const int grow = m0 + wm * WMW + (mi << 4) + r0;
#pragma unroll
      for (int ni = 0; ni < BNF; ++ni) {
        const int gcol = n0 + wn * WNW + (ni << 4) + c0;
#pragma unroll
        for (int rr = 0; rr < 4; ++rr)
          Cz[(long long)(grow + rr) * p.ldc + gcol] = acc[mi][ni][rr] * p.scale;
      }
    }
  }
}

// =====================================================================
// gemmPV: PV GEMM (out = P @ V), 256x128, BK=64, 8 waves (4x2), THREE
// LDS buffers (144KB) + counted VMC(6) never-drain (r9-verified
// rotation; BK=64 variant). stage(t+2) at TOP of tile t into buf
// (t+2)%3 = buf (t-1)%3 whose reads completed before end-of-(t-1)
// barrier. lgkm counts identical to gemm2 (12-outstanding sequence).
// =====================================================================
__global__ __launch_bounds__(512) void gemmPV(GP p) {
  constexpr int ABUF = 256 * 128, BBUF = 128 * 128;
  extern __shared__ char smem[];            // 147456 = 3*(32768+16384)
  char* smA = smem;                         // buf b at b*ABUF
  char* smB = smem + 3 * ABUF;              // buf b at b*BBUF

  const int tid = threadIdx.x;
  const int lane = tid & 63;
  const int wid = tid >> 6;
  const int wm = wid >> 1, wn = wid & 1;    // 4x2 waves, tile 64x64

  // XCD swizzle, grid (8,8,4) = 256 WGs
  const int gx = gridDim.x, gy = gridDim.y;
  const int nwg = gx * gy * (int)gridDim.z;
  int orig = blockIdx.x + gx * (blockIdx.y + gy * blockIdx.z);
  int qq = nwg >> 3, rr_ = nwg & 7;
  int xcd = orig & 7, sl = orig >> 3;
  int wg = (xcd < rr_ ? xcd * (qq + 1) : rr_ * (qq + 1) + (xcd - rr_) * qq) + sl;
  int bx = wg % gx;
  int t2 = wg / gx;
  int by = t2 % gy;
  int z  = t2 / gy;

  const int m0 = by * 256, n0 = bx * 128;

  const long long lda2 = (long long)p.lda * 2;
  const long long ldb2 = (long long)p.ldb * 2;
  const char* Abase = (const char*)(p.A + (long long)z * p.batchA) + (long long)m0 * lda2;
  const char* Bbase = (const char*)(p.B + (long long)z * p.batchB) + (long long)n0 * ldb2;

  const int trow = tid >> 3;
  const int cs = (((tid & 7) ^ (trow & 7)) << 4);
  const char* srcA = Abase + (long long)trow * lda2 + cs;
  const char* srcB = Bbase + (long long)trow * ldb2 + cs;

  const int NT = p.K >> 6;                  // 32

  const int aRowB = ((wm * 64 + (lane & 15)) << 7);
  const int bRowB = ((wn * 64 + (lane & 15)) << 7);
  const int csw = (lane & 7) << 4;
  const int ck0 = (((lane >> 4) << 4)) ^ csw;
  const int ck1 = ((((lane >> 4) << 4)) | 64) ^ csw;

  f32x4 acc[4][4];
#pragma unroll
  for (int i = 0; i < 4; ++i)
#pragma unroll
    for (int j = 0; j < 4; ++j) acc[i][j] = (f32x4){0.f, 0.f, 0.f, 0.f};

  bf16x8 aLo[2][2], aHi[2][2], bLo[2][2], bHi[2][2];

  auto stage = [&](int t, int b) {          // 4 A-chunks + 2 B-chunks
    char* dA = smA + b * ABUF + (tid << 4);
    char* dB = smB + b * BBUF + (tid << 4);
    const char* sA = srcA + (long long)t * 128;
    const char* sB = srcB + (long long)t * 128;
#pragma unroll
    for (int c = 0; c < 4; ++c) G2L(sA + (long long)c * (lda2 << 6), dA + c * 8192);
#pragma unroll
    for (int c = 0; c < 2; ++c) G2L(sB + (long long)c * (ldb2 << 6), dB + c * 8192);
  };
  auto readAh = [&](int b, int half, bf16x8 (&dst)[2][2]) {
    const char* ra = smA + b * ABUF + aRowB + half * 4096;
#pragma unroll
    for (int mi = 0; mi < 2; ++mi) {
      dst[mi][0] = *(const bf16x8*)(ra + mi * 2048 + ck0);
      dst[mi][1] = *(const bf16x8*)(ra + mi * 2048 + ck1);
    }
  };
  auto readBh = [&](int b, int half, bf16x8 (&dst)[2][2]) {
    const char* rb = smB + b * BBUF + bRowB + half * 4096;
#pragma unroll
    for (int ni = 0; ni < 2; ++ni) {
      dst[ni][0] = *(const bf16x8*)(rb + ni * 2048 + ck0);
      dst[ni][1] = *(const bf16x8*)(rb + ni * 2048 + ck1);
    }
  };
  auto quad = [&](int qa, int qb, bf16x8 (&A)[2][2], bf16x8 (&B)[2][2]) {
    __builtin_amdgcn_s_setprio(1);
#pragma unroll
    for (int mi = 0; mi < 2; ++mi)
#pragma unroll
      for (int ni = 0; ni < 2; ++ni) {
        MFMA_(acc[qa * 2 + mi][qb * 2 + ni], A[mi][0], B[ni][0]);
        MFMA_(acc[qa * 2 + mi][qb * 2 + ni], A[mi][1], B[ni][1]);
      }
    __builtin_amdgcn_s_setprio(0);
  };

  int b0 = 0, b1 = 1, b2 = 2;

  stage(0, 0); stage(1, 1);                 // 12 outstanding
  VMC(6);                                   // tile0 retired; tile1 flies
  __builtin_amdgcn_s_barrier();
  readAh(0, 0, aLo); readBh(0, 0, bLo);     // 8 lgkm
  SB0();

  for (int t = 0; t < NT; ++t) {
    if (t + 2 < NT) stage(t + 2, b2);       // 12 vmem outstanding
    readAh(b0, 1, aHi);                     // 12 lgkm
    SB0();
    LGKM(4);                                // aLo,bLo ready (aHi pends)
    quad(0, 0, aLo, bLo);
    readBh(b0, 1, bHi);                     // +4
    SB0();
    LGKM(4);                                // aHi ready (bHi pends)
    quad(1, 0, aHi, bLo);
    LGKM(0);                                // bHi ready
    quad(0, 1, aLo, bHi);
    quad(1, 1, aHi, bHi);
    if (t + 2 < NT) { VMC(6); }             // t+1 retired; t+2 in flight
    else            { VMC(0); }
    __builtin_amdgcn_s_barrier();           // all waves done with buf b0
    if (t + 1 < NT) { readAh(b1, 0, aLo); readBh(b1, 0, bLo); }
    SB0();
    int tmp = b0; b0 = b1; b1 = b2; b2 = tmp;
  }

  const int c0 = lane & 15;
  const int r0 = (lane >> 4) << 2;
  float* Cz = (float*)p.C + (long long)z * p.batchC;
#pragma unroll
  for (int mi = 0; mi < 4; ++mi) {
    const int grow = m0 + wm * 64 + (mi << 4) + r0;
#pragma unroll
    for (int ni = 0; ni < 4; ++ni) {
      const int gcol = n0 + wn * 64 + (ni << 4) + c0;
#pragma unroll
      for (int rr = 0; rr < 4; ++rr)
        Cz[(long long)(grow + rr) * p.ldc + gcol] = acc[mi][ni][rr] * p.scale;
    }
  }
}

// ---------- row softmax over S[4][2048][2048] (bf16, in place) ----------
__global__ __launch_bounds__(256) void softmax_rows(unsigned short* __restrict__ S) {
  const size_t row = blockIdx.x;
  unsigned short* pp = S + row * 2048;
  const int t = threadIdx.x, lane = t & 63, wave = t >> 6;
  u16x8 h = ((const u16x8*)pp)[t];
  float x[8];
#pragma unroll
  for (int j = 0; j < 8; ++j) x[j] = bf2f(h[j]);
  float m = x[0];
#pragma unroll
  for (int j = 1; j < 8; ++j) m = fmaxf(m, x[j]);
#pragma unroll
  for (int off = 32; off >= 1; off >>= 1) m = fmaxf(m, __shfl_xor(m, off, 64));
  __shared__ float rmax[4], rsum[4];
  if (lane == 0) rmax[wave] = m;
  __syncthreads();
  m = fmaxf(fmaxf(rmax[0], rmax[1]), fmaxf(rmax[2], rmax[3]));
  float e[8], sum = 0.f;
#pragma unroll
  for (int j = 0; j < 8; ++j) { e[j] = __expf(x[j] - m); sum += e[j]; }
#pragma unroll
  for (int off = 32; off >= 1; off >>= 1) sum += __shfl_xor(sum, off, 64);
  if (lane == 0) rsum[wave] = sum;
  __syncthreads();
  sum = rsum[0] + rsum[1] + rsum[2] + rsum[3];
  const float inv = 1.f / sum;
  u16x8 o;
#pragma unroll
  for (int j = 0; j < 8; ++j) o[j] = f2bf(e[j] * inv);
  ((u16x8*)pp)[t] = o;
}

// ---------- launch ----------
extern "C" void kernel_launch(void* const* d_in, const int* in_sizes, int n_in,
                              void* d_out, int out_size, void* d_ws, size_t ws_size,
                              hipStream_t stream) {
  const float* q  = (const float*)d_in[0];
  const float* k  = (const float*)d_in[1];
  const float* v  = (const float*)d_in[2];
  const float* Wq = (const float*)d_in[3];
  const float* bq = (const float*)d_in[4];
  const float* Wk = (const float*)d_in[5];
  const float* bk = (const float*)d_in[6];
  const float* Wv = (const float*)d_in[7];
  const float* bv = (const float*)d_in[8];

  // workspace (u16 elems): S 32MB, Wb 6MB, qb 16MB, kb 16MB, vT 16MB = 86MB
  unsigned short* S  = (unsigned short*)d_ws;
  unsigned short* Wb = S + 16777216;
  unsigned short* qb = Wb + 3145728;
  unsigned short* kb = qb + 8388608;
  unsigned short* vT = kb + 8388608;

  (void)hipFuncSetAttribute((const void*)gemmP,
      hipFuncAttributeMaxDynamicSharedMemorySize, 81920);
  (void)hipFuncSetAttribute((const void*)gemm2<256,256,128,64,EPI_SCALE>,
      hipFuncAttributeMaxDynamicSharedMemorySize, 131072);
  (void)hipFuncSetAttribute((const void*)gemmPV,
      hipFuncAttributeMaxDynamicSharedMemorySize, 147456);

  cvtW<<<3072, 256, 0, stream>>>(Wq, Wk, Wv, Wb);

  // fused q/k/v projections (r14-exact): 1536 WGs (128^2), 2 WGs/CU
  PJ pj{};
  pj.A0 = q; pj.A1 = k; pj.A2 = v;
  pj.B = Wb;
  pj.outQ = qb; pj.outK = kb; pj.outV = vT;
  pj.biasQ = bq; pj.biasK = bk; pj.biasV = bv;
  gemmP<<<dim3(8, 64, 3), 256, 81920, stream>>>(pj);

  // scores = q @ k^T * scale : per batch M=2048, N=2048, K=1024 (256 WGs)
  GP gs{};
  gs.A = qb; gs.batchA = 2097152; gs.lda = 1024;
  gs.B = kb; gs.batchB = 2097152; gs.ldb = 1024;
  gs.C = S;  gs.batchC = 4194304; gs.ldc = 2048;
  gs.K = 1024; gs.scale = 0.03125f;
  gemm2<256,256,128,64,EPI_SCALE><<<dim3(8, 8, 4), 512, 131072, stream>>>(gs);

  softmax_rows<<<8192, 256, 0, stream>>>(S);

  // out = P @ V : M=2048, N=1024, K=2048 per batch (256 WGs, 3-buf deep)
  GP gv{};
  gv.A = S;  gv.batchA = 4194304; gv.lda = 2048;
  gv.B = vT; gv.batchB = 2097152; gv.ldb = 2048;
  gv.C = (unsigned short*)d_out; gv.batchC = 2097152; gv.ldc = 1024;
  gv.K = 2048; gv.scale = 1.f;
  gemmPV<<<dim3(8, 8, 4), 512, 147456, stream>>>(gv);
}